// Round 4
// baseline (497.519 us; speedup 1.0000x reference)
//
#include <hip/hip_runtime.h>
#include <hip/hip_bf16.h>

// ---------- CSR build ----------
__global__ void k_hist(const int* __restrict__ dst, int* __restrict__ cnt, int E) {
    int e = blockIdx.x * blockDim.x + threadIdx.x;
    if (e < E) atomicAdd(&cnt[dst[e]], 1);
}

__global__ void k_scanA(const int* __restrict__ cnt, int* __restrict__ bsum, int N) {
    __shared__ int sh[256];
    int i = blockIdx.x * 256 + threadIdx.x;
    sh[threadIdx.x] = (i < N) ? cnt[i] : 0;
    __syncthreads();
    for (int off = 128; off > 0; off >>= 1) {
        if (threadIdx.x < off) sh[threadIdx.x] += sh[threadIdx.x + off];
        __syncthreads();
    }
    if (threadIdx.x == 0) bsum[blockIdx.x] = sh[0];
}

__global__ void k_scanB(int* __restrict__ bsum, int nb) {
    __shared__ int sh[1024];
    int t = threadIdx.x;
    sh[t] = (t < nb) ? bsum[t] : 0;
    __syncthreads();
    for (int off = 1; off < 1024; off <<= 1) {
        int v = (t >= off) ? sh[t - off] : 0;
        __syncthreads();
        sh[t] += v;
        __syncthreads();
    }
    if (t < nb) bsum[t] = (t == 0) ? 0 : sh[t - 1];
}

__global__ void k_scanC(const int* __restrict__ cnt, const int* __restrict__ boff,
                        int* __restrict__ row_ptr, float* __restrict__ dis, int N) {
    __shared__ int sh[256];
    int i = blockIdx.x * 256 + threadIdx.x;
    int v = (i < N) ? cnt[i] : 0;
    sh[threadIdx.x] = v;
    __syncthreads();
    for (int off = 1; off < 256; off <<= 1) {
        int u = (threadIdx.x >= off) ? sh[threadIdx.x - off] : 0;
        __syncthreads();
        sh[threadIdx.x] += u;
        __syncthreads();
    }
    if (i < N) {
        row_ptr[i] = sh[threadIdx.x] - v + boff[blockIdx.x];
        dis[i] = rsqrtf((float)v + 1.0f);
    }
}

__global__ void k_fill(const int* __restrict__ src, const int* __restrict__ dst,
                       const int* __restrict__ row_ptr, int* __restrict__ cursor,
                       int* __restrict__ csr_src, int E) {
    int e = blockIdx.x * blockDim.x + threadIdx.x;
    if (e < E) {
        int d = dst[e];
        int pos = row_ptr[d] + atomicAdd(&cursor[d], 1);
        csr_src[pos] = src[e];
    }
}

// ---------- row-looped GEMM: out[N][64] = (in[N][K] @ W[K][64]) * dis[row] ----------
// Persistent-ish blocks; W staged to LDS once per block; 4 rows per wave-iteration.
template <int K>
__global__ void __launch_bounds__(256) k_gemm_big(const float* __restrict__ in,
                                                  const float* __restrict__ W,
                                                  const float* __restrict__ dis,
                                                  float* __restrict__ out, int N) {
    __shared__ float Wl[K * 64];
    for (int i = threadIdx.x; i < K * 16; i += 256)
        ((float4*)Wl)[i] = ((const float4*)W)[i];
    __syncthreads();
    int lane = threadIdx.x & 63;
    int wid  = blockIdx.x * 4 + (threadIdx.x >> 6);
    int nw   = gridDim.x * 4;
    int ngrp = (N + 3) >> 2;
    for (int g = wid; g < ngrp; g += nw) {
        int base = g * 4;
        int r1 = min(base + 1, N - 1), r2 = min(base + 2, N - 1), r3 = min(base + 3, N - 1);
        const float4* p0 = (const float4*)(in + (size_t)base * K);
        const float4* p1 = (const float4*)(in + (size_t)r1 * K);
        const float4* p2 = (const float4*)(in + (size_t)r2 * K);
        const float4* p3 = (const float4*)(in + (size_t)r3 * K);
        float acc0 = 0.f, acc1 = 0.f, acc2 = 0.f, acc3 = 0.f;
#pragma unroll 4
        for (int kg = 0; kg < K / 4; ++kg) {
            float4 a0 = p0[kg], a1 = p1[kg], a2 = p2[kg], a3 = p3[kg];
            int k = kg * 4;
            float w0 = Wl[(k + 0) * 64 + lane];
            float w1 = Wl[(k + 1) * 64 + lane];
            float w2 = Wl[(k + 2) * 64 + lane];
            float w3 = Wl[(k + 3) * 64 + lane];
            acc0 = fmaf(a0.w, w3, fmaf(a0.z, w2, fmaf(a0.y, w1, fmaf(a0.x, w0, acc0))));
            acc1 = fmaf(a1.w, w3, fmaf(a1.z, w2, fmaf(a1.y, w1, fmaf(a1.x, w0, acc1))));
            acc2 = fmaf(a2.w, w3, fmaf(a2.z, w2, fmaf(a2.y, w1, fmaf(a2.x, w0, acc2))));
            acc3 = fmaf(a3.w, w3, fmaf(a3.z, w2, fmaf(a3.y, w1, fmaf(a3.x, w0, acc3))));
        }
        out[(size_t)base * 64 + lane] = acc0 * dis[base];
        if (base + 1 < N) out[(size_t)(base + 1) * 64 + lane] = acc1 * dis[r1];
        if (base + 2 < N) out[(size_t)(base + 2) * 64 + lane] = acc2 * dis[r2];
        if (base + 3 < N) out[(size_t)(base + 3) * 64 + lane] = acc3 * dis[r3];
    }
}

// ---------- CSR gather + self-loop + bias + BN stats ----------
__global__ void k_gather(const int* __restrict__ row_ptr, const int* __restrict__ cnt,
                         const int* __restrict__ csr_src, const float* __restrict__ dis,
                         const float* __restrict__ hs, const float* __restrict__ b,
                         float* __restrict__ z, float* __restrict__ stats, int N) {
    int lane = threadIdx.x & 63;
    int w    = threadIdx.x >> 6;
    float psum = 0.f, psq = 0.f;
    for (int n = blockIdx.x * 4 + w; n < N; n += gridDim.x * 4) {
        int start = row_ptr[n];
        int c     = cnt[n];
        float acc0 = hs[(size_t)n * 64 + lane], acc1 = 0.f;
        int j = 0;
        for (; j + 8 <= c; j += 8) {
            int s0 = csr_src[start + j + 0];
            int s1 = csr_src[start + j + 1];
            int s2 = csr_src[start + j + 2];
            int s3 = csr_src[start + j + 3];
            int s4 = csr_src[start + j + 4];
            int s5 = csr_src[start + j + 5];
            int s6 = csr_src[start + j + 6];
            int s7 = csr_src[start + j + 7];
            float v0 = hs[(size_t)s0 * 64 + lane];
            float v1 = hs[(size_t)s1 * 64 + lane];
            float v2 = hs[(size_t)s2 * 64 + lane];
            float v3 = hs[(size_t)s3 * 64 + lane];
            float v4 = hs[(size_t)s4 * 64 + lane];
            float v5 = hs[(size_t)s5 * 64 + lane];
            float v6 = hs[(size_t)s6 * 64 + lane];
            float v7 = hs[(size_t)s7 * 64 + lane];
            acc0 += v0 + v2 + v4 + v6;
            acc1 += v1 + v3 + v5 + v7;
        }
        for (; j < c; ++j) acc0 += hs[(size_t)csr_src[start + j] * 64 + lane];
        float v = (acc0 + acc1) * dis[n] + b[lane];
        __builtin_nontemporal_store(v, &z[(size_t)n * 64 + lane]);
        psum += v;
        psq  += v * v;
    }
    __shared__ float ssum[256], ssq[256];
    ssum[threadIdx.x] = psum;
    ssq[threadIdx.x]  = psq;
    __syncthreads();
    if (threadIdx.x < 64) {
        float s = ssum[threadIdx.x] + ssum[64 + threadIdx.x] + ssum[128 + threadIdx.x] + ssum[192 + threadIdx.x];
        float q = ssq[threadIdx.x] + ssq[64 + threadIdx.x] + ssq[128 + threadIdx.x] + ssq[192 + threadIdx.x];
        atomicAdd(&stats[threadIdx.x], s);
        atomicAdd(&stats[64 + threadIdx.x], q);
    }
}

// ---------- normalize (inline BN finalize) + (residual) + relu ----------
__global__ void k_norm(const float* __restrict__ z, const float* __restrict__ stats,
                       const float* __restrict__ g, const float* __restrict__ be,
                       const float* __restrict__ res, float* __restrict__ out,
                       float invN, int total) {
    int i = blockIdx.x * blockDim.x + threadIdx.x;
    if (i >= total) return;
    int c = i & 63;
    float mu  = stats[c] * invN;
    float var = stats[64 + c] * invN - mu * mu;
    float sc  = g[c] * rsqrtf(var + 1e-5f);
    float sh  = be[c] - mu * sc;
    float v = z[i] * sc + sh;
    if (res) v += res[i];
    out[i] = fmaxf(v, 0.f);
}

// ---------- layer-3 normalize + relu + segmented pool (batch sorted) ----------
__global__ void k_norm_pool(const float* __restrict__ z, const float* __restrict__ stats,
                            const float* __restrict__ g, const float* __restrict__ be,
                            const int* __restrict__ batch, float* __restrict__ psums,
                            float* __restrict__ pcnt, float invN, int N, int per) {
    int lane = threadIdx.x & 63;
    int wave = (blockIdx.x * blockDim.x + threadIdx.x) >> 6;
    int begin = wave * per;
    if (begin >= N) return;
    int end = begin + per; if (end > N) end = N;
    float mu  = stats[lane] * invN;
    float var = stats[64 + lane] * invN - mu * mu;
    float sc  = g[lane] * rsqrtf(var + 1e-5f);
    float sh  = be[lane] - mu * sc;
    int   cur = batch[begin];
    float run = 0.f;
    int   crun = 0;
    for (int n = begin; n < end; ++n) {
        int gg = batch[n];
        if (gg != cur) {
            atomicAdd(&psums[(size_t)cur * 64 + lane], run);
            if (lane == 0) atomicAdd(&pcnt[cur], (float)crun);
            run = 0.f; crun = 0; cur = gg;
        }
        float v = fmaxf(z[(size_t)n * 64 + lane] * sc + sh, 0.f);
        run += v; crun++;
    }
    atomicAdd(&psums[(size_t)cur * 64 + lane], run);
    if (lane == 0) atomicAdd(&pcnt[cur], (float)crun);
}

// ---------- FF branch + fusion head ----------
__global__ void k_head(const float* __restrict__ sigma, const float* __restrict__ Wf1,
                       const float* __restrict__ bf1, const float* __restrict__ Wf2,
                       const float* __restrict__ bf2, const float* __restrict__ Wfu,
                       const float* __restrict__ bfu, const float* __restrict__ sums,
                       const float* __restrict__ cnt, float* __restrict__ out) {
    int g = blockIdx.x;
    int t = threadIdx.x;  // 128 threads
    __shared__ float srow[64], f1[128], f2[64];
    if (t < 64) srow[t] = sigma[(size_t)g * 64 + t];
    __syncthreads();
    {
        float acc = bf1[t];
        for (int s = 0; s < 64; ++s) acc += srow[s] * Wf1[s * 128 + t];
        f1[t] = fmaxf(acc, 0.f);
    }
    __syncthreads();
    if (t < 64) {
        float a2 = bf2[t];
        for (int k = 0; k < 128; ++k) a2 += f1[k] * Wf2[k * 64 + t];
        f2[t] = fmaxf(a2, 0.f);
    }
    __syncthreads();
    if (t < 64) {
        float inv    = 1.0f / fmaxf(cnt[g], 1.0f);
        float pooled = sums[(size_t)g * 64 + t] * inv;
        float contrib = pooled * Wfu[t] + f2[t] * Wfu[64 + t];
#pragma unroll
        for (int o = 32; o > 0; o >>= 1) contrib += __shfl_down(contrib, o);
        if (t == 0) out[g] = contrib + bfu[0];
    }
}

extern "C" void kernel_launch(void* const* d_in, const int* in_sizes, int n_in,
                              void* d_out, int out_size, void* d_ws, size_t ws_size,
                              hipStream_t stream) {
    const float* x     = (const float*)d_in[0];
    const int*   ei    = (const int*)d_in[1];
    const int*   batch = (const int*)d_in[2];
    const float* sigma = (const float*)d_in[3];
    const float* W1 = (const float*)d_in[4];  const float* b1 = (const float*)d_in[5];
    const float* g1 = (const float*)d_in[6];  const float* be1 = (const float*)d_in[7];
    const float* W2 = (const float*)d_in[8];  const float* b2 = (const float*)d_in[9];
    const float* g2 = (const float*)d_in[10]; const float* be2 = (const float*)d_in[11];
    const float* W3 = (const float*)d_in[12]; const float* b3 = (const float*)d_in[13];
    const float* g3 = (const float*)d_in[14]; const float* be3 = (const float*)d_in[15];
    const float* Wf1 = (const float*)d_in[16]; const float* bf1 = (const float*)d_in[17];
    const float* Wf2 = (const float*)d_in[18]; const float* bf2 = (const float*)d_in[19];
    const float* Wfu = (const float*)d_in[20]; const float* bfu = (const float*)d_in[21];

    const int N = in_sizes[0] / 128;
    const int E = in_sizes[1] / 2;
    const int G = in_sizes[3] / 64;
    const int* src = ei;
    const int* dst = ei + E;

    float* ws   = (float*)d_ws;
    float* bufA = ws;                       // hs (pre-scaled gemm out)
    float* bufB = bufA + (size_t)N * 64;    // z
    float* bufC = bufB + (size_t)N * 64;    // h (activations)
    float* dis  = bufC + (size_t)N * 64;
    int*   row_ptr = (int*)(dis + N);
    int*   bsum    = row_ptr + N;
    int*   csr_src = bsum + 1024;
    // ---- contiguous zero region ----
    int*   cnt     = csr_src + E;
    int*   cursor  = cnt + N;
    float* stats1  = (float*)(cursor + N);
    float* stats2  = stats1 + 128;
    float* stats3  = stats2 + 128;
    float* psums   = stats3 + 128;
    float* pcnt    = psums + (size_t)G * 64;
    size_t zero_bytes = ((char*)(pcnt + G)) - ((char*)cnt);

    const float invN = 1.0f / (float)N;
    const int totNH  = N * 64;
    const int nb     = (N + 255) / 256;

    hipMemsetAsync(cnt, 0, zero_bytes, stream);

    // ---- CSR build + degrees ----
    k_hist<<<(E + 255) / 256, 256, 0, stream>>>(dst, cnt, E);
    k_scanA<<<nb, 256, 0, stream>>>(cnt, bsum, N);
    k_scanB<<<1, 1024, 0, stream>>>(bsum, nb);
    k_scanC<<<nb, 256, 0, stream>>>(cnt, bsum, row_ptr, dis, N);
    k_fill<<<(E + 255) / 256, 256, 0, stream>>>(src, dst, row_ptr, cursor, csr_src, E);

    // ---- layer 1 ----
    k_gemm_big<128><<<1024, 256, 0, stream>>>(x, W1, dis, bufA, N);
    k_gather<<<2048, 256, 0, stream>>>(row_ptr, cnt, csr_src, dis, bufA, b1, bufB, stats1, N);
    k_norm<<<(totNH + 255) / 256, 256, 0, stream>>>(bufB, stats1, g1, be1, nullptr, bufC, invN, totNH);

    // ---- layer 2 (residual = bufC) ----
    k_gemm_big<64><<<1024, 256, 0, stream>>>(bufC, W2, dis, bufA, N);
    k_gather<<<2048, 256, 0, stream>>>(row_ptr, cnt, csr_src, dis, bufA, b2, bufB, stats2, N);
    k_norm<<<(totNH + 255) / 256, 256, 0, stream>>>(bufB, stats2, g2, be2, bufC, bufA, invN, totNH); // h2 -> bufA

    // ---- layer 3 ----
    k_gemm_big<64><<<1024, 256, 0, stream>>>(bufA, W3, dis, bufC, N);               // hs3 -> bufC
    k_gather<<<2048, 256, 0, stream>>>(row_ptr, cnt, csr_src, dis, bufC, b3, bufB, stats3, N);

    // ---- fused normalize + relu + pool ----
    {
        const int waves = 8192;  // 2048 blocks x 4 waves
        int per = (N + waves - 1) / waves;
        k_norm_pool<<<2048, 256, 0, stream>>>(bufB, stats3, g3, be3, batch, psums, pcnt, invN, N, per);
    }

    // ---- head ----
    k_head<<<G, 128, 0, stream>>>(sigma, Wf1, bf1, Wf2, bf2, Wfu, bfu, psums, pcnt, (float*)d_out);
}